// Round 4
// baseline (170.404 us; speedup 1.0000x reference)
//
#include <hip/hip_runtime.h>
#include <hip/hip_bf16.h>
#include <hip/hip_cooperative_groups.h>

namespace cg = cooperative_groups;

typedef __attribute__((ext_vector_type(8))) short s8v;     // 8 bf16 operand
typedef __attribute__((ext_vector_type(4))) float f4v;     // fp32 accum

__device__ __forceinline__ ushort f2bf(float f) {
    unsigned u = __builtin_bit_cast(unsigned, f);
    unsigned r = (u + 0x7fffu + ((u >> 16) & 1u)) >> 16;   // RTNE
    return (ushort)r;
}

__device__ __forceinline__ void gload16(const ushort* g, ushort* l) {
    __builtin_amdgcn_global_load_lds(
        (const __attribute__((address_space(1))) unsigned*)g,
        (__attribute__((address_space(3))) unsigned*)l, 16, 0, 0);
}

// ======== stage P: x cvt+transpose (1024 jobs) + W transpose (192) + Wo cvt (64)
__device__ __forceinline__ void stageP(
    ushort* lds, const float* x, const float* Wq, const float* Wk, const float* Wv,
    const float* Wo, ushort* xb, ushort* xlc, ushort* wqT, ushort* wkT, ushort* wvT,
    ushort* wo16) {
    ushort (*t)[72] = (ushort(*)[72])lds;
    int tid = threadIdx.x;
    int r = tid >> 3, c0 = (tid & 7) * 8;
    for (int j = blockIdx.x; j < 1280; j += 256) {
        __syncthreads();
        if (j < 1024) {
            int lt = j & 15, ct = (j >> 4) & 3, b = j >> 6;
            size_t so = ((size_t)(b * 256 + ct * 64 + r)) * 1024 + lt * 64 + c0;
            float4 v0 = *(const float4*)(x + so);
            float4 v1 = *(const float4*)(x + so + 4);
            ushort4 u0 = { f2bf(v0.x), f2bf(v0.y), f2bf(v0.z), f2bf(v0.w) };
            ushort4 u1 = { f2bf(v1.x), f2bf(v1.y), f2bf(v1.z), f2bf(v1.w) };
            *(ushort4*)(xb + so) = u0;
            *(ushort4*)(xb + so + 4) = u1;
            *(ushort4*)&t[r][c0] = u0;
            *(ushort4*)&t[r][c0 + 4] = u1;
            __syncthreads();
            size_t dof = ((size_t)(b * 1024 + lt * 64 + r)) * 256 + ct * 64 + c0;
            ushort4 w0 = { t[c0][r], t[c0 + 1][r], t[c0 + 2][r], t[c0 + 3][r] };
            ushort4 w1 = { t[c0 + 4][r], t[c0 + 5][r], t[c0 + 6][r], t[c0 + 7][r] };
            *(ushort4*)(xlc + dof) = w0;
            *(ushort4*)(xlc + dof + 4) = w1;
        } else if (j < 1216) {
            int q = j - 1024;
            int tile = q & 15, h = (q >> 4) & 3, which = q >> 6;
            const float* src = which == 0 ? Wq : which == 1 ? Wk : Wv;
            ushort* dst = which == 0 ? wqT : which == 1 ? wkT : wvT;
            int tr = tile >> 2, tc = tile & 3;
            const float* s = src + (size_t)h * 65536 + (size_t)(tr * 64 + r) * 256 + tc * 64 + c0;
            float4 v0 = *(const float4*)(s);
            float4 v1 = *(const float4*)(s + 4);
            ushort4 u0 = { f2bf(v0.x), f2bf(v0.y), f2bf(v0.z), f2bf(v0.w) };
            ushort4 u1 = { f2bf(v1.x), f2bf(v1.y), f2bf(v1.z), f2bf(v1.w) };
            *(ushort4*)&t[r][c0] = u0;
            *(ushort4*)&t[r][c0 + 4] = u1;
            __syncthreads();
            ushort* d = dst + (size_t)h * 65536 + (size_t)(tc * 64 + r) * 256 + tr * 64 + c0;
            ushort4 w0 = { t[c0][r], t[c0 + 1][r], t[c0 + 2][r], t[c0 + 3][r] };
            ushort4 w1 = { t[c0 + 4][r], t[c0 + 5][r], t[c0 + 6][r], t[c0 + 7][r] };
            *(ushort4*)(d) = w0;
            *(ushort4*)(d + 4) = w1;
        } else {
            int q = j - 1216;
            size_t i = (size_t)q * 4096 + (size_t)tid * 8;
            float4 v0 = *(const float4*)(Wo + i);
            float4 v1 = *(const float4*)(Wo + i + 4);
            ushort4 u0 = { f2bf(v0.x), f2bf(v0.y), f2bf(v0.z), f2bf(v0.w) };
            ushort4 u1 = { f2bf(v1.x), f2bf(v1.y), f2bf(v1.z), f2bf(v1.w) };
            *(ushort4*)(wo16 + i) = u0;
            *(ushort4*)(wo16 + i + 4) = u1;
        }
    }
}

// ======== 64x64 tile, 8 waves: K split in halves across two 4-wave groups,
// 4-slot LDS pipeline per group, counted vmcnt, cross-group LDS reduce.
__device__ __forceinline__ void gemm64x8(
    const ushort* Xb, const ushort* Yb, int ldx, int ldy, ushort* lds,
    int row0, int col0, int K, ushort* O, int ldo) {
    const int tid = threadIdx.x, wave = tid >> 6, lane = tid & 63;
    const int g = wave >> 2, w4 = wave & 3;
    const int wr = w4 >> 1, wc = w4 & 1;
    const int rA = lane & 15, kg = lane >> 4;
    const int srow = w4 * 16 + (lane >> 2);
    const int scol = ((lane & 3) ^ ((lane >> 3) & 3)) * 8;
    const int K2 = K >> 1, NT = K2 >> 5, kb = g * K2;
    ushort* LA = lds + g * 16384;    // 4 slots x 2048
    ushort* LB = LA + 8192;
    f4v acc[2][2] = {};
    __syncthreads();                 // protect LDS vs previous phase reads
    const ushort* gx = Xb + (size_t)(row0 + srow) * ldx + kb + scol;
    const ushort* gy = Yb + (size_t)(col0 + srow) * ldy + kb + scol;
    gload16(gx,      LA + w4 * 512);
    gload16(gy,      LB + w4 * 512);
    gload16(gx + 32, LA + 2048 + w4 * 512);
    gload16(gy + 32, LB + 2048 + w4 * 512);
    for (int t = 0; t < NT; ++t) {
        if (t + 2 < NT) {
            int s2 = (t + 2) & 3, kt = (t + 2) << 5;
            gload16(gx + kt, LA + s2 * 2048 + w4 * 512);
            gload16(gy + kt, LB + s2 * 2048 + w4 * 512);
            asm volatile("s_waitcnt vmcnt(4)" ::: "memory");
        } else if (t + 1 < NT) {
            asm volatile("s_waitcnt vmcnt(2)" ::: "memory");
        } else {
            asm volatile("s_waitcnt vmcnt(0)" ::: "memory");
        }
        __builtin_amdgcn_s_barrier();
        __builtin_amdgcn_sched_barrier(0);
        const ushort* pa = LA + (t & 3) * 2048;
        const ushort* pb = LB + (t & 3) * 2048;
        s8v a[2], b[2];
#pragma unroll
        for (int m = 0; m < 2; ++m) {
            int row = wr * 32 + m * 16 + rA;
            a[m] = *(const s8v*)&pa[row * 32 + ((kg ^ ((row >> 1) & 3)) << 3)];
        }
#pragma unroll
        for (int n = 0; n < 2; ++n) {
            int row = wc * 32 + n * 16 + rA;
            b[n] = *(const s8v*)&pb[row * 32 + ((kg ^ ((row >> 1) & 3)) << 3)];
        }
#pragma unroll
        for (int m = 0; m < 2; ++m)
#pragma unroll
            for (int n = 0; n < 2; ++n)
                acc[m][n] = __builtin_amdgcn_mfma_f32_16x16x32_bf16(a[m], b[n], acc[m][n], 0, 0, 0);
    }
    __syncthreads();
    float* red = (float*)lds;
    if (g == 1) {
#pragma unroll
        for (int m = 0; m < 2; ++m)
#pragma unroll
            for (int n = 0; n < 2; ++n)
                *(f4v*)&red[(w4 * 64 + lane) * 16 + (m * 2 + n) * 4] = acc[m][n];
    }
    __syncthreads();
    if (g == 0) {
        int r4 = (lane >> 4) * 4, cl = lane & 15;
#pragma unroll
        for (int m = 0; m < 2; ++m)
#pragma unroll
            for (int n = 0; n < 2; ++n) {
                f4v o = *(const f4v*)&red[(w4 * 64 + lane) * 16 + (m * 2 + n) * 4];
                f4v s = acc[m][n] + o;
                int row = row0 + wr * 32 + m * 16 + r4;
                int col = col0 + wc * 32 + n * 16 + cl;
#pragma unroll
                for (int r = 0; r < 4; ++r)
                    O[(size_t)(row + r) * ldo + col] = f2bf(s[r]);
            }
    }
}

// ======== 128x128 tile, 8 waves (2 row-groups x 4 col-groups), acc 4x2
template<int OBF>
__device__ __forceinline__ void gemm128x8(
    const ushort* Xb, const ushort* Yb, int ldx, int ldy, ushort* lds,
    int row0, int col0, int K, void* Oraw, int ldo, const float* bias) {
    const int tid = threadIdx.x, wave = tid >> 6, lane = tid & 63;
    const int wr = wave >> 2, wc = wave & 3;
    const int rA = lane & 15, kg = lane >> 4;
    const int sr = lane >> 2;
    const int scol = ((lane & 3) ^ ((lane >> 3) & 3)) * 8;
    const int NT = K >> 5;
    ushort* LA = lds;                // 4 slots x 4096
    ushort* LB = lds + 16384;
    f4v acc[4][2] = {};
    __syncthreads();
    const ushort* gx = Xb + (size_t)(row0 + wave * 16 + sr) * ldx + scol;
    const ushort* gy = Yb + (size_t)(col0 + wave * 16 + sr) * ldy + scol;
#pragma unroll
    for (int p = 0; p < 2; ++p) {
        gload16(gx + p * 32, LA + p * 4096 + wave * 512);
        gload16(gy + p * 32, LB + p * 4096 + wave * 512);
    }
    for (int t = 0; t < NT; ++t) {
        if (t + 2 < NT) {
            int s2 = (t + 2) & 3, kt = (t + 2) << 5;
            gload16(gx + kt, LA + s2 * 4096 + wave * 512);
            gload16(gy + kt, LB + s2 * 4096 + wave * 512);
            asm volatile("s_waitcnt vmcnt(4)" ::: "memory");
        } else if (t + 1 < NT) {
            asm volatile("s_waitcnt vmcnt(2)" ::: "memory");
        } else {
            asm volatile("s_waitcnt vmcnt(0)" ::: "memory");
        }
        __builtin_amdgcn_s_barrier();
        __builtin_amdgcn_sched_barrier(0);
        const ushort* pa = LA + (t & 3) * 4096;
        const ushort* pb = LB + (t & 3) * 4096;
        s8v a[4], b[2];
#pragma unroll
        for (int m = 0; m < 4; ++m) {
            int row = wr * 64 + m * 16 + rA;
            a[m] = *(const s8v*)&pa[row * 32 + ((kg ^ ((row >> 1) & 3)) << 3)];
        }
#pragma unroll
        for (int n = 0; n < 2; ++n) {
            int row = wc * 32 + n * 16 + rA;
            b[n] = *(const s8v*)&pb[row * 32 + ((kg ^ ((row >> 1) & 3)) << 3)];
        }
#pragma unroll
        for (int m = 0; m < 4; ++m)
#pragma unroll
            for (int n = 0; n < 2; ++n)
                acc[m][n] = __builtin_amdgcn_mfma_f32_16x16x32_bf16(a[m], b[n], acc[m][n], 0, 0, 0);
    }
    int r4 = (lane >> 4) * 4, cl = lane & 15;
    if (OBF) {
        ushort* O = (ushort*)Oraw;
#pragma unroll
        for (int m = 0; m < 4; ++m)
#pragma unroll
            for (int n = 0; n < 2; ++n) {
                int row = row0 + wr * 64 + m * 16 + r4;
                int col = col0 + wc * 32 + n * 16 + cl;
#pragma unroll
                for (int r = 0; r < 4; ++r)
                    O[(size_t)(row + r) * ldo + col] = f2bf(acc[m][n][r]);
            }
    } else {
        float* O = (float*)Oraw;
#pragma unroll
        for (int m = 0; m < 4; ++m)
#pragma unroll
            for (int n = 0; n < 2; ++n) {
                int row = row0 + wr * 64 + m * 16 + r4;
                int col = col0 + wc * 32 + n * 16 + cl;
#pragma unroll
                for (int r = 0; r < 4; ++r)
                    O[(size_t)(row + r) * ldo + col] = acc[m][n][r] + bias[row + r];
            }
    }
}

// ======== per-stage bodies
__device__ __forceinline__ void stageSA(
    ushort* lds, const ushort* xb, const ushort* wqT, const ushort* wkT,
    const ushort* wo16, const ushort* wvT, ushort* S16, ushort* A16, ushort* BT) {
    int j = blockIdx.x;
    int xcd = j & 7, idx = j >> 3;
    int b = 2 * xcd + (idx >> 4), tile = idx & 15;
    const ushort* Xb = xb + (size_t)b * 262144;
    gemm64x8(Xb, Xb, 1024, 1024, lds, (tile >> 2) * 64, (tile & 3) * 64, 1024,
             S16 + (size_t)b * 65536, 256);
    if (j < 128) {
        int which = j >> 6, q = j & 63, h = q >> 4, t2 = q & 15;
        if (which == 0)
            gemm64x8(wqT + h * 65536, wkT + h * 65536, 256, 256, lds,
                     (t2 >> 2) * 64, (t2 & 3) * 64, 256, A16 + h * 65536, 256);
        else
            gemm64x8(wo16 + h * 256, wvT + h * 65536, 1024, 256, lds,
                     (t2 >> 2) * 64, (t2 & 3) * 64, 256, BT + h * 256, 1024);
    }
}

__device__ __forceinline__ void stageT1(
    ushort* lds, const ushort* A16, const ushort* S16, ushort* T1) {
    int j = blockIdx.x;
    int xcd = j & 7, idx = j >> 3;
    int b = 2 * xcd + (idx >> 4), h = (idx >> 2) & 3, tile = idx & 3;
    gemm128x8<1>(A16 + h * 65536, S16 + (size_t)b * 65536, 256, 256, lds,
                 (tile >> 1) * 128, (tile & 1) * 128, 256,
                 T1 + (size_t)b * 262144 + h * 256, 1024, nullptr);
}

__device__ __forceinline__ void stageGT(
    ushort* lds, const ushort* BT, const ushort* T1, ushort* GT) {
    int j = blockIdx.x;
    int xcd = j & 7, idx = j >> 3;
    int b = 2 * xcd + (idx >> 4), tile = idx & 15;
    gemm64x8(BT, T1 + (size_t)b * 262144, 1024, 1024, lds,
             (tile >> 2) * 64, (tile & 3) * 64, 1024, GT + (size_t)b * 65536, 256);
}

__device__ __forceinline__ void stageOUT(
    ushort* lds, const ushort* GT, const ushort* xlc, float* out, const float* bias) {
    int j = blockIdx.x;
    int xcd = j & 7, idx = j >> 3;
    int b = 2 * xcd + (idx >> 4), tile = idx & 15;
    gemm128x8<0>(GT + (size_t)b * 65536, xlc + (size_t)b * 262144, 256, 256, lds,
                 (tile >> 3) * 128, (tile & 7) * 128, 256,
                 out + (size_t)b * 262144, 1024, bias);
}

// ======== cooperative mega-kernel
__global__ __launch_bounds__(512, 2) void mega(
    const float* __restrict__ x, const float* __restrict__ Wq, const float* __restrict__ Wk,
    const float* __restrict__ Wv, const float* __restrict__ Wo, const float* __restrict__ Wb,
    float* __restrict__ out, ushort* xb, ushort* xlc, ushort* wqT, ushort* wkT,
    ushort* wvT, ushort* wo16, ushort* A16, ushort* BT, ushort* S16, ushort* GT) {
    __shared__ __align__(16) ushort lds[32768];
    cg::grid_group grid = cg::this_grid();
    stageP(lds, x, Wq, Wk, Wv, Wo, xb, xlc, wqT, wkT, wvT, wo16);
    grid.sync();
    stageSA(lds, xb, wqT, wkT, wo16, wvT, S16, A16, BT);
    grid.sync();
    stageT1(lds, A16, S16, xb);          // T1 aliases xb
    grid.sync();
    stageGT(lds, BT, xb, GT);
    grid.sync();
    stageOUT(lds, GT, xlc, out, Wb);
}

// ======== fallback: same stages as separate launches
__global__ __launch_bounds__(512, 2) void kP(
    const float* x, const float* Wq, const float* Wk, const float* Wv, const float* Wo,
    ushort* xb, ushort* xlc, ushort* wqT, ushort* wkT, ushort* wvT, ushort* wo16) {
    __shared__ __align__(16) ushort lds[32768];
    stageP(lds, x, Wq, Wk, Wv, Wo, xb, xlc, wqT, wkT, wvT, wo16);
}
__global__ __launch_bounds__(512, 2) void kSA(
    const ushort* xb, const ushort* wqT, const ushort* wkT, const ushort* wo16,
    const ushort* wvT, ushort* S16, ushort* A16, ushort* BT) {
    __shared__ __align__(16) ushort lds[32768];
    stageSA(lds, xb, wqT, wkT, wo16, wvT, S16, A16, BT);
}
__global__ __launch_bounds__(512, 2) void kT1(const ushort* A16, const ushort* S16, ushort* T1) {
    __shared__ __align__(16) ushort lds[32768];
    stageT1(lds, A16, S16, T1);
}
__global__ __launch_bounds__(512, 2) void kGT(const ushort* BT, const ushort* T1, ushort* GT) {
    __shared__ __align__(16) ushort lds[32768];
    stageGT(lds, BT, T1, GT);
}
__global__ __launch_bounds__(512, 2) void kOUT(
    const ushort* GT, const ushort* xlc, float* out, const float* bias) {
    __shared__ __align__(16) ushort lds[32768];
    stageOUT(lds, GT, xlc, out, bias);
}

extern "C" void kernel_launch(void* const* d_in, const int* in_sizes, int n_in,
                              void* d_out, int out_size, void* d_ws, size_t ws_size,
                              hipStream_t stream) {
    const float* x  = (const float*)d_in[0];
    const float* Wq = (const float*)d_in[1];
    const float* Wk = (const float*)d_in[2];
    const float* Wv = (const float*)d_in[3];
    const float* Wo = (const float*)d_in[4];
    const float* Wb = (const float*)d_in[5];
    float* outp = (float*)d_out;

    char* ws = (char*)d_ws;
    ushort* xb   = (ushort*)(ws + 0);          // 8 MB; aliased as T1 after S consumed
    ushort* xlc  = (ushort*)(ws + 8388608);    // 8 MB
    ushort* wqT  = (ushort*)(ws + 16777216);
    ushort* wkT  = (ushort*)(ws + 17301504);
    ushort* wvT  = (ushort*)(ws + 17825792);
    ushort* wo16 = (ushort*)(ws + 18350080);
    ushort* A16  = (ushort*)(ws + 18874368);
    ushort* BT   = (ushort*)(ws + 19398656);   // [256][1024]
    ushort* S16  = (ushort*)(ws + 19922944);   // [16][256][256]
    ushort* GT   = (ushort*)(ws + 22020096);   // [16][256][256]

    void* args[] = { &x, &Wq, &Wk, &Wv, &Wo, &Wb, &outp, &xb, &xlc, &wqT, &wkT,
                     &wvT, &wo16, &A16, &BT, &S16, &GT };
    hipError_t e = hipLaunchCooperativeKernel((void*)mega, dim3(256), dim3(512),
                                              args, 0, stream);
    if (e != hipSuccess) {
        (void)hipGetLastError();   // clear sticky error, use fallback path
        hipLaunchKernelGGL(kP,  dim3(256), dim3(512), 0, stream,
                           x, Wq, Wk, Wv, Wo, xb, xlc, wqT, wkT, wvT, wo16);
        hipLaunchKernelGGL(kSA, dim3(256), dim3(512), 0, stream,
                           xb, wqT, wkT, wo16, wvT, S16, A16, BT);
        hipLaunchKernelGGL(kT1, dim3(256), dim3(512), 0, stream, A16, S16, xb);
        hipLaunchKernelGGL(kGT, dim3(256), dim3(512), 0, stream, BT, xb, GT);
        hipLaunchKernelGGL(kOUT, dim3(256), dim3(512), 0, stream, GT, xlc, outp, Wb);
    }
}

// Round 5
// 42.827 us; speedup vs baseline: 3.9789x; 3.9789x over previous
//
#include <hip/hip_runtime.h>
#include <hip/hip_bf16.h>

typedef __attribute__((ext_vector_type(8))) short s8v;     // 8 bf16 = 16B
typedef __attribute__((ext_vector_type(4))) float f4v;     // fp32 accum

__device__ __forceinline__ ushort f2bf(float f) {
    unsigned u = __builtin_bit_cast(unsigned, f);
    unsigned r = (u + 0x7fffu + ((u >> 16) & 1u)) >> 16;   // RTNE
    return (ushort)r;
}

// LDS k-slot swizzle: uses row bits 1-4 so both stride-1 and stride-8 row
// access patterns spread across banks (old (row>>1)&3 was period-8).
__device__ __forceinline__ int fsw(int row) { return ((row >> 1) ^ (row >> 3)) & 3; }

__device__ __forceinline__ void gload16(const ushort* g, ushort* l) {
    __builtin_amdgcn_global_load_lds(
        (const __attribute__((address_space(1))) unsigned*)g,
        (__attribute__((address_space(3))) unsigned*)l, 16, 0, 0);
}

__device__ __forceinline__ void cvtw16(ushort* p, float4 a, float4 b) {
    s8v u;
    u[0] = (short)f2bf(a.x); u[1] = (short)f2bf(a.y);
    u[2] = (short)f2bf(a.z); u[3] = (short)f2bf(a.w);
    u[4] = (short)f2bf(b.x); u[5] = (short)f2bf(b.y);
    u[6] = (short)f2bf(b.z); u[7] = (short)f2bf(b.w);
    *(s8v*)p = u;
}

// scatter-write 8 bf16 down a column (transposed staging), swizzled
__device__ __forceinline__ void scatw(ushort* L, int c8, int d, float4 a, float4 b) {
    float v[8] = { a.x, a.y, a.z, a.w, b.x, b.y, b.z, b.w };
#pragma unroll
    for (int i = 0; i < 8; ++i) {
        int row = c8 + i;
        L[row * 32 + (((d >> 3) ^ fsw(row)) << 3) + (d & 7)] = f2bf(v[i]);
    }
}

// ===== 64x64 tile S-GEMM from fp32 source (D = X @ Y^T, ld 1024), 8 waves
// split-K (2 groups x K/2). Reg-staged cvt fp32->bf16, 4-slot LDS pipeline,
// loads issued 3 iters ahead, raw barrier + lgkmcnt (never full vmcnt drain).
template<int NT>   // NT = (K/2)/32
__device__ __forceinline__ void gemmS(
    const float* __restrict__ Xb, const float* __restrict__ Yb,
    ushort* lds, int row0, int col0, ushort* __restrict__ O, int ldo) {
    const int tid = threadIdx.x, wave = tid >> 6, lane = tid & 63;
    const int g = wave >> 2, w4 = wave & 3;
    const int wr = w4 >> 1, wc = w4 & 1;
    const int rA = lane & 15, kg = lane >> 4;
    const int tg = tid & 255;
    const int srow = tg >> 2, slot = tg & 3;
    const int kb = g * (NT * 32);
    ushort* LA = lds + g * 16384;
    ushort* LB = LA + 8192;
    const int wadr = srow * 32 + ((slot ^ fsw(srow)) << 3);
    const float* gx = Xb + (size_t)(row0 + srow) * 1024 + kb + slot * 8;
    const float* gy = Yb + (size_t)(col0 + srow) * 1024 + kb + slot * 8;
    f4v acc[2][2] = {};

    float4 bx[4][2], by[4][2];
#pragma unroll
    for (int p = 0; p < 3; ++p) {
        bx[p][0] = *(const float4*)(gx + p * 32);
        bx[p][1] = *(const float4*)(gx + p * 32 + 4);
        by[p][0] = *(const float4*)(gy + p * 32);
        by[p][1] = *(const float4*)(gy + p * 32 + 4);
    }
    cvtw16(LA + wadr, bx[0][0], bx[0][1]);
    cvtw16(LB + wadr, by[0][0], by[0][1]);

#pragma unroll
    for (int t = 0; t < NT; ++t) {
        if (t + 3 < NT) {
            const int bi = (t + 3) & 3;
            bx[bi][0] = *(const float4*)(gx + (t + 3) * 32);
            bx[bi][1] = *(const float4*)(gx + (t + 3) * 32 + 4);
            by[bi][0] = *(const float4*)(gy + (t + 3) * 32);
            by[bi][1] = *(const float4*)(gy + (t + 3) * 32 + 4);
        }
        if (t + 1 < NT) {
            const int bi = (t + 1) & 3;
            cvtw16(LA + ((t + 1) & 3) * 2048 + wadr, bx[bi][0], bx[bi][1]);
            cvtw16(LB + ((t + 1) & 3) * 2048 + wadr, by[bi][0], by[bi][1]);
        }
        asm volatile("s_waitcnt lgkmcnt(0)" ::: "memory");
        __builtin_amdgcn_s_barrier();
        __builtin_amdgcn_sched_barrier(0);
        const ushort* pa = LA + (t & 3) * 2048;
        const ushort* pb = LB + (t & 3) * 2048;
        s8v a[2], b[2];
#pragma unroll
        for (int m = 0; m < 2; ++m) {
            int row = wr * 32 + m * 16 + rA;
            a[m] = *(const s8v*)&pa[row * 32 + ((kg ^ fsw(row)) << 3)];
        }
#pragma unroll
        for (int n = 0; n < 2; ++n) {
            int row = wc * 32 + n * 16 + rA;
            b[n] = *(const s8v*)&pb[row * 32 + ((kg ^ fsw(row)) << 3)];
        }
#pragma unroll
        for (int m = 0; m < 2; ++m)
#pragma unroll
            for (int n = 0; n < 2; ++n)
                acc[m][n] = __builtin_amdgcn_mfma_f32_16x16x32_bf16(a[m], b[n], acc[m][n], 0, 0, 0);
    }
    // split-K reduce + store
    __syncthreads();
    float* red = (float*)lds;
    if (g == 1) {
#pragma unroll
        for (int m = 0; m < 2; ++m)
#pragma unroll
            for (int n = 0; n < 2; ++n)
                *(f4v*)&red[(w4 * 64 + lane) * 16 + (m * 2 + n) * 4] = acc[m][n];
    }
    __syncthreads();
    if (g == 0) {
        int r4 = (lane >> 4) * 4, cl = lane & 15;
#pragma unroll
        for (int m = 0; m < 2; ++m)
#pragma unroll
            for (int n = 0; n < 2; ++n) {
                f4v o = *(const f4v*)&red[(w4 * 64 + lane) * 16 + (m * 2 + n) * 4];
                f4v s = acc[m][n] + o;
                int row = row0 + wr * 32 + m * 16 + r4;
                int col = col0 + wc * 32 + n * 16 + cl;
#pragma unroll
                for (int r = 0; r < 4; ++r)
                    O[(size_t)(row + r) * ldo + col] = f2bf(s[r]);
            }
    }
}

// ===== 64x64 weight-GEMM from fp32 (K=256, split-K NT=4/group).
// XT=1: X transposed from W[h][d][c] (A = Wq^T@Wk). XT=0: X straight ld1024 (Wo).
// Y always transposed from W[h][d][c].
template<int XT>
__device__ __forceinline__ void gemmWT(
    const float* __restrict__ Xw, const float* __restrict__ Yw,
    ushort* lds, int row0, int col0, ushort* __restrict__ O, int ldo) {
    const int NT = 4;
    const int tid = threadIdx.x, wave = tid >> 6, lane = tid & 63;
    const int g = wave >> 2, w4 = wave & 3;
    const int wr = w4 >> 1, wc = w4 & 1;
    const int rA = lane & 15, kg = lane >> 4;
    const int tg = tid & 255;
    const int kb = g * 128;
    ushort* LA = lds + g * 16384;
    ushort* LB = LA + 8192;
    // transposed-staging map
    const int dT = tg >> 3, c8 = (tg & 7) * 8;
    // straight-staging map (XT=0 X side)
    const int srow = tg >> 2, slot = tg & 3;
    const int wadr = srow * 32 + ((slot ^ fsw(srow)) << 3);
    f4v acc[2][2] = {};

    float4 bx[4][2], by[4][2];
#pragma unroll
    for (int p = 0; p < 3; ++p) {
        if (XT) {
            bx[p][0] = *(const float4*)(Xw + (size_t)(kb + p * 32 + dT) * 256 + row0 + c8);
            bx[p][1] = *(const float4*)(Xw + (size_t)(kb + p * 32 + dT) * 256 + row0 + c8 + 4);
        } else {
            bx[p][0] = *(const float4*)(Xw + (size_t)(row0 + srow) * 1024 + kb + p * 32 + slot * 8);
            bx[p][1] = *(const float4*)(Xw + (size_t)(row0 + srow) * 1024 + kb + p * 32 + slot * 8 + 4);
        }
        by[p][0] = *(const float4*)(Yw + (size_t)(kb + p * 32 + dT) * 256 + col0 + c8);
        by[p][1] = *(const float4*)(Yw + (size_t)(kb + p * 32 + dT) * 256 + col0 + c8 + 4);
    }
    if (XT) scatw(LA, c8, dT, bx[0][0], bx[0][1]);
    else    cvtw16(LA + wadr, bx[0][0], bx[0][1]);
    scatw(LB, c8, dT, by[0][0], by[0][1]);

#pragma unroll
    for (int t = 0; t < NT; ++t) {
        if (t + 3 < NT) {
            const int bi = (t + 3) & 3;
            if (XT) {
                bx[bi][0] = *(const float4*)(Xw + (size_t)(kb + (t + 3) * 32 + dT) * 256 + row0 + c8);
                bx[bi][1] = *(const float4*)(Xw + (size_t)(kb + (t + 3) * 32 + dT) * 256 + row0 + c8 + 4);
            } else {
                bx[bi][0] = *(const float4*)(Xw + (size_t)(row0 + srow) * 1024 + kb + (t + 3) * 32 + slot * 8);
                bx[bi][1] = *(const float4*)(Xw + (size_t)(row0 + srow) * 1024 + kb + (t + 3) * 32 + slot * 8 + 4);
            }
            by[bi][0] = *(const float4*)(Yw + (size_t)(kb + (t + 3) * 32 + dT) * 256 + col0 + c8);
            by[bi][1] = *(const float4*)(Yw + (size_t)(kb + (t + 3) * 32 + dT) * 256 + col0 + c8 + 4);
        }
        if (t + 1 < NT) {
            const int bi = (t + 1) & 3;
            ushort* la = LA + ((t + 1) & 3) * 2048;
            ushort* lb = LB + ((t + 1) & 3) * 2048;
            if (XT) scatw(la, c8, dT, bx[bi][0], bx[bi][1]);
            else    cvtw16(la + wadr, bx[bi][0], bx[bi][1]);
            scatw(lb, c8, dT, by[bi][0], by[bi][1]);
        }
        asm volatile("s_waitcnt lgkmcnt(0)" ::: "memory");
        __builtin_amdgcn_s_barrier();
        __builtin_amdgcn_sched_barrier(0);
        const ushort* pa = LA + (t & 3) * 2048;
        const ushort* pb = LB + (t & 3) * 2048;
        s8v a[2], b[2];
#pragma unroll
        for (int m = 0; m < 2; ++m) {
            int row = wr * 32 + m * 16 + rA;
            a[m] = *(const s8v*)&pa[row * 32 + ((kg ^ fsw(row)) << 3)];
        }
#pragma unroll
        for (int n = 0; n < 2; ++n) {
            int row = wc * 32 + n * 16 + rA;
            b[n] = *(const s8v*)&pb[row * 32 + ((kg ^ fsw(row)) << 3)];
        }
#pragma unroll
        for (int m = 0; m < 2; ++m)
#pragma unroll
            for (int n = 0; n < 2; ++n)
                acc[m][n] = __builtin_amdgcn_mfma_f32_16x16x32_bf16(a[m], b[n], acc[m][n], 0, 0, 0);
    }
    __syncthreads();
    float* red = (float*)lds;
    if (g == 1) {
#pragma unroll
        for (int m = 0; m < 2; ++m)
#pragma unroll
            for (int n = 0; n < 2; ++n)
                *(f4v*)&red[(w4 * 64 + lane) * 16 + (m * 2 + n) * 4] = acc[m][n];
    }
    __syncthreads();
    if (g == 0) {
        int r4 = (lane >> 4) * 4, cl = lane & 15;
#pragma unroll
        for (int m = 0; m < 2; ++m)
#pragma unroll
            for (int n = 0; n < 2; ++n) {
                f4v o = *(const f4v*)&red[(w4 * 64 + lane) * 16 + (m * 2 + n) * 4];
                f4v s = acc[m][n] + o;
                int row = row0 + wr * 32 + m * 16 + r4;
                int col = col0 + wc * 32 + n * 16 + cl;
#pragma unroll
                for (int r = 0; r < 4; ++r)
                    O[(size_t)(row + r) * ldo + col] = f2bf(s[r]);
            }
    }
}

// ===== 64x64 tile bf16 GEMM (gload_lds), 8-wave split-K — for GT (K=1024)
__device__ __forceinline__ void gemm64x8(
    const ushort* __restrict__ Xb, const ushort* __restrict__ Yb,
    int ldx, int ldy, ushort* lds, int row0, int col0, int K,
    ushort* __restrict__ O, int ldo) {
    const int tid = threadIdx.x, wave = tid >> 6, lane = tid & 63;
    const int g = wave >> 2, w4 = wave & 3;
    const int wr = w4 >> 1, wc = w4 & 1;
    const int rA = lane & 15, kg = lane >> 4;
    const int srow = w4 * 16 + (lane >> 2);
    const int scol = ((lane & 3) ^ fsw(srow)) * 8;
    const int K2 = K >> 1, NT = K2 >> 5, kb = g * K2;
    ushort* LA = lds + g * 16384;
    ushort* LB = LA + 8192;
    f4v acc[2][2] = {};
    __syncthreads();
    const ushort* gx = Xb + (size_t)(row0 + srow) * ldx + kb + scol;
    const ushort* gy = Yb + (size_t)(col0 + srow) * ldy + kb + scol;
    gload16(gx,      LA + w4 * 512);
    gload16(gy,      LB + w4 * 512);
    gload16(gx + 32, LA + 2048 + w4 * 512);
    gload16(gy + 32, LB + 2048 + w4 * 512);
    for (int t = 0; t < NT; ++t) {
        if (t + 2 < NT) {
            int s2 = (t + 2) & 3, kt = (t + 2) << 5;
            gload16(gx + kt, LA + s2 * 2048 + w4 * 512);
            gload16(gy + kt, LB + s2 * 2048 + w4 * 512);
            asm volatile("s_waitcnt vmcnt(4)" ::: "memory");
        } else if (t + 1 < NT) {
            asm volatile("s_waitcnt vmcnt(2)" ::: "memory");
        } else {
            asm volatile("s_waitcnt vmcnt(0)" ::: "memory");
        }
        __builtin_amdgcn_s_barrier();
        __builtin_amdgcn_sched_barrier(0);
        const ushort* pa = LA + (t & 3) * 2048;
        const ushort* pb = LB + (t & 3) * 2048;
        s8v a[2], b[2];
#pragma unroll
        for (int m = 0; m < 2; ++m) {
            int row = wr * 32 + m * 16 + rA;
            a[m] = *(const s8v*)&pa[row * 32 + ((kg ^ fsw(row)) << 3)];
        }
#pragma unroll
        for (int n = 0; n < 2; ++n) {
            int row = wc * 32 + n * 16 + rA;
            b[n] = *(const s8v*)&pb[row * 32 + ((kg ^ fsw(row)) << 3)];
        }
#pragma unroll
        for (int m = 0; m < 2; ++m)
#pragma unroll
            for (int n = 0; n < 2; ++n)
                acc[m][n] = __builtin_amdgcn_mfma_f32_16x16x32_bf16(a[m], b[n], acc[m][n], 0, 0, 0);
    }
    __syncthreads();
    float* red = (float*)lds;
    if (g == 1) {
#pragma unroll
        for (int m = 0; m < 2; ++m)
#pragma unroll
            for (int n = 0; n < 2; ++n)
                *(f4v*)&red[(w4 * 64 + lane) * 16 + (m * 2 + n) * 4] = acc[m][n];
    }
    __syncthreads();
    if (g == 0) {
        int r4 = (lane >> 4) * 4, cl = lane & 15;
#pragma unroll
        for (int m = 0; m < 2; ++m)
#pragma unroll
            for (int n = 0; n < 2; ++n) {
                f4v o = *(const f4v*)&red[(w4 * 64 + lane) * 16 + (m * 2 + n) * 4];
                f4v s = acc[m][n] + o;
                int row = row0 + wr * 32 + m * 16 + r4;
                int col = col0 + wc * 32 + n * 16 + cl;
#pragma unroll
                for (int r = 0; r < 4; ++r)
                    O[(size_t)(row + r) * ldo + col] = f2bf(s[r]);
            }
    }
}

// ===== 128x128 tile bf16 GEMM (gload_lds), 8 waves (2x4), acc 4x2 — K=256 stages
template<int OBF>
__device__ __forceinline__ void gemm128x8(
    const ushort* __restrict__ Xb, const ushort* __restrict__ Yb,
    int ldx, int ldy, ushort* lds, int row0, int col0, int K,
    void* __restrict__ Oraw, int ldo, const float* __restrict__ bias) {
    const int tid = threadIdx.x, wave = tid >> 6, lane = tid & 63;
    const int wr = wave >> 2, wc = wave & 3;
    const int rA = lane & 15, kg = lane >> 4;
    const int srow = wave * 16 + (lane >> 2);
    const int scol = ((lane & 3) ^ fsw(srow)) * 8;
    const int NT = K >> 5;
    ushort* LA = lds;
    ushort* LB = lds + 16384;
    f4v acc[4][2] = {};
    __syncthreads();
    const ushort* gx = Xb + (size_t)(row0 + srow) * ldx + scol;
    const ushort* gy = Yb + (size_t)(col0 + srow) * ldy + scol;
#pragma unroll
    for (int p = 0; p < 2; ++p) {
        gload16(gx + p * 32, LA + p * 4096 + wave * 512);
        gload16(gy + p * 32, LB + p * 4096 + wave * 512);
    }
    for (int t = 0; t < NT; ++t) {
        if (t + 2 < NT) {
            int s2 = (t + 2) & 3, kt = (t + 2) << 5;
            gload16(gx + kt, LA + s2 * 4096 + wave * 512);
            gload16(gy + kt, LB + s2 * 4096 + wave * 512);
            asm volatile("s_waitcnt vmcnt(4)" ::: "memory");
        } else if (t + 1 < NT) {
            asm volatile("s_waitcnt vmcnt(2)" ::: "memory");
        } else {
            asm volatile("s_waitcnt vmcnt(0)" ::: "memory");
        }
        __builtin_amdgcn_s_barrier();
        __builtin_amdgcn_sched_barrier(0);
        const ushort* pa = LA + (t & 3) * 4096;
        const ushort* pb = LB + (t & 3) * 4096;
        s8v a[4], b[2];
#pragma unroll
        for (int m = 0; m < 4; ++m) {
            int row = wr * 64 + m * 16 + rA;
            a[m] = *(const s8v*)&pa[row * 32 + ((kg ^ fsw(row)) << 3)];
        }
#pragma unroll
        for (int n = 0; n < 2; ++n) {
            int row = wc * 32 + n * 16 + rA;
            b[n] = *(const s8v*)&pb[row * 32 + ((kg ^ fsw(row)) << 3)];
        }
#pragma unroll
        for (int m = 0; m < 4; ++m)
#pragma unroll
            for (int n = 0; n < 2; ++n)
                acc[m][n] = __builtin_amdgcn_mfma_f32_16x16x32_bf16(a[m], b[n], acc[m][n], 0, 0, 0);
    }
    int r4 = (lane >> 4) * 4, cl = lane & 15;
    if (OBF) {
        ushort* O = (ushort*)Oraw;
#pragma unroll
        for (int m = 0; m < 4; ++m)
#pragma unroll
            for (int n = 0; n < 2; ++n) {
                int row = row0 + wr * 64 + m * 16 + r4;
                int col = col0 + wc * 32 + n * 16 + cl;
#pragma unroll
                for (int r = 0; r < 4; ++r)
                    O[(size_t)(row + r) * ldo + col] = f2bf(acc[m][n][r]);
            }
    } else {
        float* O = (float*)Oraw;
#pragma unroll
        for (int m = 0; m < 4; ++m)
#pragma unroll
            for (int n = 0; n < 2; ++n) {
                int row = row0 + wr * 64 + m * 16 + r4;
                int col = col0 + wc * 32 + n * 16 + cl;
#pragma unroll
                for (int r = 0; r < 4; ++r)
                    O[(size_t)(row + r) * ldo + col] = acc[m][n][r] + bias[row + r];
            }
    }
}

// ===== kernel 1: S (direct fp32 x) + A + BT + xlc-transpose jobs
__global__ __launch_bounds__(512, 2) void kSP(
    const float* __restrict__ x, const float* __restrict__ Wq,
    const float* __restrict__ Wk, const float* __restrict__ Wv,
    const float* __restrict__ Wo,
    ushort* __restrict__ xlc, ushort* __restrict__ S16,
    ushort* __restrict__ A16, ushort* __restrict__ BT) {
    __shared__ __align__(16) ushort lds[32768];
    const int bid = blockIdx.x, tid = threadIdx.x;
    {   // S tile (XCD-grouped by batch)
        int xcd = bid & 7, idx = bid >> 3;
        int b = 2 * xcd + (idx >> 4), tile = idx & 15;
        const float* Xb = x + (size_t)b * 262144;
        gemmS<16>(Xb, Xb, lds, (tile >> 2) * 64, (tile & 3) * 64,
                  S16 + (size_t)b * 65536, 256);
    }
    // jobs: 0..1023 xlc transpose, 1024..1087 A tiles, 1088..1151 BT tiles
    for (int jid = bid; jid < 1152; jid += 256) {
        __syncthreads();
        if (jid < 1024) {
            ushort (*t)[72] = (ushort(*)[72])lds;
            int lt = jid & 15, ct = (jid >> 4) & 3, b2 = jid >> 6;
            int r = tid >> 3, c0 = (tid & 7) * 8;
            size_t so = (size_t)(b2 * 256 + ct * 64 + r) * 1024 + lt * 64 + c0;
            float4 v0 = *(const float4*)(x + so);
            float4 v1 = *(const float4*)(x + so + 4);
            ushort4 u0 = { f2bf(v0.x), f2bf(v0.y), f2bf(v0.z), f2bf(v0.w) };
            ushort4 u1 = { f2bf(v1.x), f2bf(v1.y), f2bf(v1.z), f2bf(v1.w) };
            *(ushort4*)&t[r][c0] = u0;
            *(ushort4*)&t[r][c0 + 4] = u1;
            __syncthreads();
            size_t dof = (size_t)(b2 * 1024 + lt * 64 + r) * 256 + ct * 64 + c0;
            ushort4 w0 = { t[c0][r], t[c0 + 1][r], t[c0 + 2][r], t[c0 + 3][r] };
            ushort4 w1 = { t[c0 + 4][r], t[c0 + 5][r], t[c0 + 6][r], t[c0 + 7][r] };
            *(ushort4*)(xlc + dof) = w0;
            *(ushort4*)(xlc + dof + 4) = w1;
        } else if (jid < 1088) {
            int q = jid - 1024, h = q >> 4, t2 = q & 15;
            gemmWT<1>(Wq + (size_t)h * 65536, Wk + (size_t)h * 65536, lds,
                      (t2 >> 2) * 64, (t2 & 3) * 64, A16 + (size_t)h * 65536, 256);
        } else {
            int q = jid - 1088, h = q >> 4, t2 = q & 15;
            gemmWT<0>(Wo + (size_t)h * 256, Wv + (size_t)h * 65536, lds,
                      (t2 >> 2) * 64, (t2 & 3) * 64, BT + (size_t)h * 256, 1024);
        }
    }
}

// ===== kernel 2: T1[b][c0][h*256+c'] = A_h @ S_b^T
__global__ __launch_bounds__(512, 2) void kT1(
    const ushort* __restrict__ A16, const ushort* __restrict__ S16,
    ushort* __restrict__ T1) {
    __shared__ __align__(16) ushort lds[32768];
    int j = blockIdx.x, xcd = j & 7, idx = j >> 3;
    int b = 2 * xcd + (idx >> 4), h = (idx >> 2) & 3, tile = idx & 3;
    gemm128x8<1>(A16 + (size_t)h * 65536, S16 + (size_t)b * 65536, 256, 256, lds,
                 (tile >> 1) * 128, (tile & 1) * 128, 256,
                 T1 + (size_t)b * 262144 + h * 256, 1024, nullptr);
}

// ===== kernel 3: GT_b = BTflat @ T1_b^T (K=1024)
__global__ __launch_bounds__(512, 2) void kGT(
    const ushort* __restrict__ BT, const ushort* __restrict__ T1,
    ushort* __restrict__ GT) {
    __shared__ __align__(16) ushort lds[32768];
    int j = blockIdx.x, xcd = j & 7, idx = j >> 3;
    int b = 2 * xcd + (idx >> 4), tile = idx & 15;
    gemm64x8(BT, T1 + (size_t)b * 262144, 1024, 1024, lds,
             (tile >> 2) * 64, (tile & 3) * 64, 1024, GT + (size_t)b * 65536, 256);
}

// ===== kernel 4: OUT_b[c][l] = GT_b @ xlc_b^T + bias[c] (fp32)
__global__ __launch_bounds__(512, 2) void kOUT(
    const ushort* __restrict__ GT, const ushort* __restrict__ xlc,
    float* __restrict__ out, const float* __restrict__ bias) {
    __shared__ __align__(16) ushort lds[32768];
    int j = blockIdx.x, xcd = j & 7, idx = j >> 3;
    int b = 2 * xcd + (idx >> 4), tile = idx & 15;
    gemm128x8<0>(GT + (size_t)b * 65536, xlc + (size_t)b * 262144, 256, 256, lds,
                 (tile >> 3) * 128, (tile & 7) * 128, 256,
                 out + (size_t)b * 262144, 1024, bias);
}

extern "C" void kernel_launch(void* const* d_in, const int* in_sizes, int n_in,
                              void* d_out, int out_size, void* d_ws, size_t ws_size,
                              hipStream_t stream) {
    const float* x  = (const float*)d_in[0];
    const float* Wq = (const float*)d_in[1];
    const float* Wk = (const float*)d_in[2];
    const float* Wv = (const float*)d_in[3];
    const float* Wo = (const float*)d_in[4];
    const float* Wb = (const float*)d_in[5];

    char* ws = (char*)d_ws;
    ushort* xlc = (ushort*)(ws + 0);           // [16][1024][256] bf16, 8 MB
    ushort* T1  = (ushort*)(ws + 8388608);     // [16][256][1024] bf16, 8 MB
    ushort* S16 = (ushort*)(ws + 16777216);    // [16][256][256]  bf16, 2 MB
    ushort* GT  = (ushort*)(ws + 18874368);    // [16][256][256]  bf16, 2 MB
    ushort* A16 = (ushort*)(ws + 20971520);    // [4][256][256]   bf16, 512 KB
    ushort* BT  = (ushort*)(ws + 21495808);    // [256][1024]     bf16, 512 KB

    hipLaunchKernelGGL(kSP,  dim3(256), dim3(512), 0, stream,
                       x, Wq, Wk, Wv, Wo, xlc, S16, A16, BT);
    hipLaunchKernelGGL(kT1,  dim3(256), dim3(512), 0, stream, A16, S16, T1);
    hipLaunchKernelGGL(kGT,  dim3(256), dim3(512), 0, stream, BT, T1, GT);
    hipLaunchKernelGGL(kOUT, dim3(256), dim3(512), 0, stream, GT, xlc, (float*)d_out, Wb);
}